// Round 10
// baseline (254.382 us; speedup 1.0000x reference)
//
#include <hip/hip_runtime.h>

#define B_ 16
#define C_ 256
#define T_ 2048
#define K_TOP 256

typedef float  f32x4 __attribute__((ext_vector_type(4)));
typedef short  s16x8 __attribute__((ext_vector_type(8)));

#define GLOAD_LDS16(gsrc, ldst)                                                     \
    __builtin_amdgcn_global_load_lds(                                               \
        (const __attribute__((address_space(1))) void*)(gsrc),                      \
        (__attribute__((address_space(3))) void*)(ldst), 16, 0, 0)

static inline __device__ ushort f2bf(float f) {
    unsigned u = __float_as_uint(f);
    u += 0x7FFF + ((u >> 16) & 1);          // round-to-nearest-even
    return (ushort)(u >> 16);
}

// 16-bit monotone fixed-point key of v (v in [-1.01, 1.03]):
// f = clamp(v+3, [2,4)) has constant exponent -> mantissa bits [22:7] are a
// uniform monotone 16-bit encoding (resolution ~6e-5).
static inline __device__ unsigned key16_of(float v) {
    float f = v + 3.0f;
    f = fminf(fmaxf(f, 2.0f), __uint_as_float(0x407FFFFFu));
    return (__float_as_uint(f) >> 7) & 0xFFFFu;
}

// ---------------------------------------------------------------------------
// K1: inverse column norms  invn[b,t] = 1 / max(||x[b,:,t]||, 1e-12)
// ---------------------------------------------------------------------------
__global__ __launch_bounds__(256) void norm_kernel(const float* __restrict__ x,
                                                   float* __restrict__ invn) {
    const int b = blockIdx.y;
    const int t = blockIdx.x * 256 + threadIdx.x;
    const float* xp = x + (size_t)b * C_ * T_ + t;
    float acc = 0.f;
#pragma unroll 8
    for (int c = 0; c < C_; ++c) {
        float v = xp[(size_t)c * T_];
        acc = fmaf(v, v, acc);
    }
    invn[b * T_ + t] = 1.0f / fmaxf(sqrtf(acc), 1e-12f);
}

// ---------------------------------------------------------------------------
// K1b: xt[b][t][c] = bf16( x[b][c][t] * invn[b][t] )   (transpose + normalize)
//      also xb[b][c][t] = bf16( x[b][c][t] )           (same layout as x)
// ---------------------------------------------------------------------------
__global__ __launch_bounds__(256) void xt_kernel(const float* __restrict__ x,
                                                 const float* __restrict__ invn,
                                                 ushort* __restrict__ xt,
                                                 ushort* __restrict__ xb) {
    const int b  = blockIdx.z;
    const int c0 = blockIdx.y * 64;
    const int t0 = blockIdx.x * 64;
    const float* Xb = x + (size_t)b * C_ * T_;
    ushort* Ob = xt + (size_t)b * T_ * C_;
    __shared__ float tile[64][65];
    const int tid = threadIdx.x;

#pragma unroll
    for (int it = 0; it < 4; ++it) {
        int ch = tid + it * 256;
        int r  = ch >> 4;
        int c4 = (ch & 15) << 2;
        float4 v = *(const float4*)(Xb + (size_t)(c0 + r) * T_ + t0 + c4);
        tile[r][c4 + 0] = v.x;
        tile[r][c4 + 1] = v.y;
        tile[r][c4 + 2] = v.z;
        tile[r][c4 + 3] = v.w;
        if (xb) {
            ushort4 w;
            w.x = f2bf(v.x); w.y = f2bf(v.y); w.z = f2bf(v.z); w.w = f2bf(v.w);
            *(ushort4*)(xb + (size_t)b * C_ * T_ + (size_t)(c0 + r) * T_ + t0 + c4) = w;
        }
    }
    __syncthreads();
#pragma unroll
    for (int it = 0; it < 4; ++it) {
        int ch = tid + it * 256;
        int r2  = ch >> 4;
        int cc4 = (ch & 15) << 2;
        float sc = invn[b * T_ + t0 + r2];
        ushort4 w;
        w.x = f2bf(tile[cc4 + 0][r2] * sc);
        w.y = f2bf(tile[cc4 + 1][r2] * sc);
        w.z = f2bf(tile[cc4 + 2][r2] * sc);
        w.w = f2bf(tile[cc4 + 3][r2] * sc);
        *(ushort4*)(Ob + (size_t)(t0 + r2) * C_ + c0 + cc4) = w;
    }
}

// ---------------------------------------------------------------------------
// K2: sim[b,t,s] = sum_c xt[t][c]*xt[s][c]   (bf16 MFMA, 128x128 tile)
// Segmented over 8 batches per launch (sim half fits 256MB L3 -> select hits
// L3). 1-D grid (2048) + XCD-chunked swizzle. Cached stores (select reuses).
// ---------------------------------------------------------------------------
__global__ __launch_bounds__(256) void sim_mfma(const ushort* __restrict__ xt,
                                                float* __restrict__ sim,
                                                int b0) {
    const int bid  = blockIdx.x;
    const int bid2 = (bid & 7) * (2048 >> 3) + (bid >> 3);   // bijective, 8 XCD chunks
    const int b    = b0 + (bid2 >> 8);
    const int rem  = bid2 & 255;
    const int t0   = (rem >> 4) * 128;
    const int s0   = (rem & 15) * 128;
    const ushort* Xb = xt + (size_t)b * T_ * C_;

    __shared__ ushort Al[128 * 64];
    __shared__ ushort Bl[128 * 64];

    const int tid  = threadIdx.x;
    const int lane = tid & 63;
    const int wv   = tid >> 6;
    const int wr   = (wv >> 1) * 64;
    const int wc   = (wv & 1) * 64;
    const int lr   = lane & 15;
    const int lg   = lane >> 4;

    f32x4 acc[4][4] = {};

    for (int k0 = 0; k0 < C_; k0 += 64) {
        __syncthreads();
#pragma unroll
        for (int it = 0; it < 4; ++it) {
            int idx = it * 256 + tid;
            int r   = idx >> 3;
            int c8  = (idx & 7) << 3;
            GLOAD_LDS16(Xb + (size_t)(t0 + r) * C_ + k0 + c8, &Al[idx * 8]);
            GLOAD_LDS16(Xb + (size_t)(s0 + r) * C_ + k0 + c8, &Bl[idx * 8]);
        }
        __syncthreads();
#pragma unroll
        for (int kk = 0; kk < 2; ++kk) {
            s16x8 af[4], bf[4];
#pragma unroll
            for (int i = 0; i < 4; ++i)
                af[i] = *(const s16x8*)&Al[(wr + i * 16 + lr) * 64 + kk * 32 + lg * 8];
#pragma unroll
            for (int j = 0; j < 4; ++j)
                bf[j] = *(const s16x8*)&Bl[(wc + j * 16 + lr) * 64 + kk * 32 + lg * 8];
#pragma unroll
            for (int i = 0; i < 4; ++i)
#pragma unroll
                for (int j = 0; j < 4; ++j)
                    acc[i][j] = __builtin_amdgcn_mfma_f32_16x16x32_bf16(af[i], bf[j], acc[i][j], 0, 0, 0);
        }
    }

    float* Sb = sim + (size_t)b * T_ * T_;
#pragma unroll
    for (int i = 0; i < 4; ++i)
#pragma unroll
        for (int j = 0; j < 4; ++j)
#pragma unroll
            for (int reg = 0; reg < 4; ++reg) {
                int t = t0 + wr + i * 16 + lg * 4 + reg;
                int s = s0 + wc + j * 16 + lr;
                Sb[(size_t)t * T_ + s] = acc[i][j][reg];
            }
}

// ---------------------------------------------------------------------------
// K3 v3: per-row k-th largest via 2-round radix on 16-bit fixed-point keys.
// Wave-per-row; row0 offsets into the current batch segment.
// ---------------------------------------------------------------------------
__global__ __launch_bounds__(256) void select_kernel(const float* __restrict__ sim,
                                                     float* __restrict__ cutoff,
                                                     float* __restrict__ isum,
                                                     ushort* __restrict__ wmat,
                                                     int row0) {
    __shared__ int h_all[4][1024];   // per-wave: 256 bins x 4 interleaved copies
    __shared__ int m_all[4][256];    // per-wave: merged bins
    const int tid  = threadIdx.x;
    const int wv   = tid >> 6;
    const int lane = tid & 63;
    int* h = h_all[wv];
    int* m = m_all[wv];
    const int row = row0 + blockIdx.x * 4 + wv;
    const float* srow = sim + (size_t)row * T_;

    // load 2048 values (coalesced) + 16-bit keys
    float    vals[32];
    unsigned k16[32];
#pragma unroll
    for (int j = 0; j < 8; ++j) {
        float4 v = ((const float4*)srow)[j * 64 + lane];
        vals[4 * j + 0] = v.x; vals[4 * j + 1] = v.y;
        vals[4 * j + 2] = v.z; vals[4 * j + 3] = v.w;
    }
#pragma unroll
    for (int j = 0; j < 32; ++j) k16[j] = key16_of(vals[j]);

    unsigned prefixB = 0;
    int kk = K_TOP;

#pragma unroll
    for (int round = 0; round < 2; ++round) {
        int4 z = {0, 0, 0, 0};
#pragma unroll
        for (int i = 0; i < 4; ++i) *(int4*)&h[i * 256 + (lane << 2)] = z;
        __builtin_amdgcn_wave_barrier();
        const int copy = lane & 3;
#pragma unroll
        for (int j = 0; j < 32; ++j) {
            unsigned ky = k16[j];
            bool active = (round == 0) || ((ky >> 8) == prefixB);
            int bin = (round == 0) ? (int)(ky >> 8) : (int)(ky & 255u);
            if (active) atomicAdd(&h[(bin << 2) | copy], 1);
        }
        __builtin_amdgcn_wave_barrier();
#pragma unroll
        for (int i = 0; i < 4; ++i) {
            int4 hv = *(const int4*)&h[(i * 64 + lane) << 2];
            m[i * 64 + lane] = hv.x + hv.y + hv.z + hv.w;
        }
        __builtin_amdgcn_wave_barrier();
        int4 mv = *(const int4*)&m[lane << 2];
        int cnt = mv.x + mv.y + mv.z + mv.w;
        int sc = __shfl(cnt, 63 - lane);         // reverse
#pragma unroll
        for (int off = 1; off < 64; off <<= 1) {
            int t = __shfl_up(sc, off);
            if (lane >= off) sc += t;
        }
        int S = __shfl(sc, 63 - lane);           // count with bin >= 4l
        int Sex = S - cnt;
        bool crossing = (S >= kk) && (Sex < kk);
        int sel = 0, kk2 = 0;
        if (crossing) {
            int rem = kk - Sex;
            int a3 = mv.w;
            int a2 = a3 + mv.z;
            int a1 = a2 + mv.y;
            if (rem <= a3)      { sel = 4 * lane + 3; kk2 = rem; }
            else if (rem <= a2) { sel = 4 * lane + 2; kk2 = rem - a3; }
            else if (rem <= a1) { sel = 4 * lane + 1; kk2 = rem - a2; }
            else                { sel = 4 * lane + 0; kk2 = rem - a1; }
        }
        unsigned long long bal = __ballot(crossing);
        int src = (int)(__ffsll((long long)bal) - 1);
        sel = __shfl(sel, src);
        kk2 = __shfl(kk2, src);
        prefixB = (round == 0) ? (unsigned)sel : ((prefixB << 8) | (unsigned)sel);
        kk = kk2;
    }
    const unsigned K16 = prefixB;

    // sum + min of kept values
    float s = 0.f, mn = 3.402823e38f;
#pragma unroll
    for (int j = 0; j < 32; ++j) {
        if (k16[j] >= K16) { s += vals[j]; mn = fminf(mn, vals[j]); }
    }
#pragma unroll
    for (int off = 32; off > 0; off >>= 1) {
        s  += __shfl_down(s, off);
        mn  = fminf(mn, __shfl_down(mn, off));
    }
    float tot = __shfl(s, 0);
    float cut = __shfl(mn, 0);
    if (tot == 0.f) tot = 1.f;
    const float iv = 1.0f / tot;
    if (lane == 0) {
        cutoff[row] = cut;
        isum[row]   = iv;
    }
    if (wmat) {
        ushort* wrow = wmat + (size_t)row * T_;
#pragma unroll
        for (int j = 0; j < 8; ++j) {
            ushort4 wq;
            wq.x = (k16[4*j+0] >= K16) ? f2bf(vals[4*j+0] * iv) : (ushort)0;
            wq.y = (k16[4*j+1] >= K16) ? f2bf(vals[4*j+1] * iv) : (ushort)0;
            wq.z = (k16[4*j+2] >= K16) ? f2bf(vals[4*j+2] * iv) : (ushort)0;
            wq.w = (k16[4*j+3] >= K16) ? f2bf(vals[4*j+3] * iv) : (ushort)0;
            *(ushort4*)(wrow + 4 * (j * 64 + lane)) = wq;
        }
    }
}

// ---------------------------------------------------------------------------
// K4 v2: out0[b,c,t] = x[b,c,t] + sum_s w[t,s]*xb[c,s]   (pure bf16 GEMM)
// 1-D grid + XCD-chunked swizzle. NT store on out0 (final, write-only).
// ---------------------------------------------------------------------------
__global__ __launch_bounds__(256) void out_mfma_v2(const float* __restrict__ x,
                                                   const ushort* __restrict__ xb,
                                                   const ushort* __restrict__ wmat,
                                                   float* __restrict__ out0) {
    const int bid  = blockIdx.x;
    const int bid2 = (bid & 7) * (512 >> 3) + (bid >> 3);
    const int b    = bid2 >> 5;
    const int rem  = bid2 & 31;
    const int t0   = (rem >> 1) * 128;
    const int c0   = (rem & 1) * 128;
    const float*  Xb = x    + (size_t)b * C_ * T_;
    const ushort* Ab = xb   + (size_t)b * C_ * T_;
    const ushort* Wb = wmat + (size_t)b * T_ * T_;

    __shared__ ushort Al[128 * 64];
    __shared__ ushort Bl[128 * 64];

    const int tid  = threadIdx.x;
    const int lane = tid & 63;
    const int wv   = tid >> 6;
    const int wr   = (wv >> 1) * 64;
    const int wc   = (wv & 1) * 64;
    const int lr   = lane & 15;
    const int lg   = lane >> 4;

    f32x4 acc[4][4] = {};

    for (int k0 = 0; k0 < T_; k0 += 64) {
        __syncthreads();
#pragma unroll
        for (int it = 0; it < 4; ++it) {
            int idx = it * 256 + tid;
            int r   = idx >> 3;
            int c8  = (idx & 7) << 3;
            GLOAD_LDS16(Ab + (size_t)(c0 + r) * T_ + k0 + c8, &Al[idx * 8]);
            GLOAD_LDS16(Wb + (size_t)(t0 + r) * T_ + k0 + c8, &Bl[idx * 8]);
        }
        __syncthreads();
#pragma unroll
        for (int kk = 0; kk < 2; ++kk) {
            s16x8 af[4], bf[4];
#pragma unroll
            for (int i = 0; i < 4; ++i)
                af[i] = *(const s16x8*)&Al[(wr + i * 16 + lr) * 64 + kk * 32 + lg * 8];
#pragma unroll
            for (int j = 0; j < 4; ++j)
                bf[j] = *(const s16x8*)&Bl[(wc + j * 16 + lr) * 64 + kk * 32 + lg * 8];
#pragma unroll
            for (int i = 0; i < 4; ++i)
#pragma unroll
                for (int j = 0; j < 4; ++j)
                    acc[i][j] = __builtin_amdgcn_mfma_f32_16x16x32_bf16(af[i], bf[j], acc[i][j], 0, 0, 0);
        }
    }

#pragma unroll
    for (int i = 0; i < 4; ++i)
#pragma unroll
        for (int j = 0; j < 4; ++j)
#pragma unroll
            for (int reg = 0; reg < 4; ++reg) {
                int c = c0 + wr + i * 16 + lg * 4 + reg;
                int t = t0 + wc + j * 16 + lr;
                float r = acc[i][j][reg] + Xb[(size_t)c * T_ + t];
                __builtin_nontemporal_store(r, &out0[((size_t)(b * C_ + c)) * T_ + t]);
            }
}

// ---------------------------------------------------------------------------
// K4 fallback (R3 version): f32 sim staging with threshold+convert
// ---------------------------------------------------------------------------
__global__ __launch_bounds__(256) void out_mfma(const float* __restrict__ x,
                                                const float* __restrict__ sim,
                                                const float* __restrict__ cutoff,
                                                const float* __restrict__ isum,
                                                float* __restrict__ out0) {
    const int b  = blockIdx.z;
    const int c0 = blockIdx.y * 128;
    const int t0 = blockIdx.x * 128;
    const float* Xb = x   + (size_t)b * C_ * T_;
    const float* Sb = sim + (size_t)b * T_ * T_;

    __shared__ ushort Al[128 * 72];
    __shared__ ushort Bl[128 * 72];
    __shared__ float cut_l[128];
    __shared__ float isv_l[128];

    const int tid  = threadIdx.x;
    const int lane = tid & 63;
    const int wv   = tid >> 6;
    const int wr   = (wv >> 1) * 64;
    const int wc   = (wv & 1) * 64;
    const int lr   = lane & 15;
    const int lg   = lane >> 4;

    if (tid < 128) {
        cut_l[tid] = cutoff[b * T_ + t0 + tid];
        isv_l[tid] = isum  [b * T_ + t0 + tid];
    }

    f32x4 acc[4][4] = {};

    for (int k0 = 0; k0 < T_; k0 += 64) {
        __syncthreads();
#pragma unroll
        for (int it = 0; it < 4; ++it) {
            int ch = tid + it * 256;
            int r  = ch >> 3;
            int c8 = (ch & 7) << 3;
            const float4* pa = (const float4*)(Xb + (size_t)(c0 + r) * T_ + k0 + c8);
            float4 a0 = pa[0], a1 = pa[1];
            ushort aw[8];
            aw[0]=f2bf(a0.x); aw[1]=f2bf(a0.y); aw[2]=f2bf(a0.z); aw[3]=f2bf(a0.w);
            aw[4]=f2bf(a1.x); aw[5]=f2bf(a1.y); aw[6]=f2bf(a1.z); aw[7]=f2bf(a1.w);
            *(s16x8*)&Al[r * 72 + c8] = *(const s16x8*)aw;
            const float4* pb = (const float4*)(Sb + (size_t)(t0 + r) * T_ + k0 + c8);
            float4 b0 = pb[0], b1 = pb[1];
            float cut = cut_l[r], sc = isv_l[r];
            ushort bw[8];
            bw[0]=f2bf(b0.x >= cut ? b0.x * sc : 0.f);
            bw[1]=f2bf(b0.y >= cut ? b0.y * sc : 0.f);
            bw[2]=f2bf(b0.z >= cut ? b0.z * sc : 0.f);
            bw[3]=f2bf(b0.w >= cut ? b0.w * sc : 0.f);
            bw[4]=f2bf(b1.x >= cut ? b1.x * sc : 0.f);
            bw[5]=f2bf(b1.y >= cut ? b1.y * sc : 0.f);
            bw[6]=f2bf(b1.z >= cut ? b1.z * sc : 0.f);
            bw[7]=f2bf(b1.w >= cut ? b1.w * sc : 0.f);
            *(s16x8*)&Bl[r * 72 + c8] = *(const s16x8*)bw;
        }
        __syncthreads();
#pragma unroll
        for (int kk = 0; kk < 2; ++kk) {
            s16x8 af[4], bf[4];
#pragma unroll
            for (int i = 0; i < 4; ++i)
                af[i] = *(const s16x8*)&Al[(wr + i * 16 + lr) * 72 + kk * 32 + lg * 8];
#pragma unroll
            for (int j = 0; j < 4; ++j)
                bf[j] = *(const s16x8*)&Bl[(wc + j * 16 + lr) * 72 + kk * 32 + lg * 8];
#pragma unroll
            for (int i = 0; i < 4; ++i)
#pragma unroll
                for (int j = 0; j < 4; ++j)
                    acc[i][j] = __builtin_amdgcn_mfma_f32_16x16x32_bf16(af[i], bf[j], acc[i][j], 0, 0, 0);
        }
    }

#pragma unroll
    for (int i = 0; i < 4; ++i)
#pragma unroll
        for (int j = 0; j < 4; ++j)
#pragma unroll
            for (int reg = 0; reg < 4; ++reg) {
                int c = c0 + wr + i * 16 + lg * 4 + reg;
                int t = t0 + wc + j * 16 + lr;
                out0[((size_t)(b * C_ + c)) * T_ + t] = acc[i][j][reg] + Xb[(size_t)c * T_ + t];
            }
}

// ---------------------------------------------------------------------------
extern "C" void kernel_launch(void* const* d_in, const int* in_sizes, int n_in,
                              void* d_out, int out_size, void* d_ws, size_t ws_size,
                              hipStream_t stream) {
    const float* x = (const float*)d_in[0];
    float* out0 = (float*)d_out;                              // (B,C,T)
    float* sim  = out0 + (size_t)B_ * C_ * T_;                // (B,T,T)

    ushort* xt = (ushort*)d_out;   // scratch in out0 region until out writes

    // workspace layout
    float* invn   = (float*)d_ws;                             // B*T
    float* cutoff = invn + B_ * T_;                           // B*T
    float* isv    = cutoff + B_ * T_;                          // B*T
    char*  ws_end = (char*)(isv + B_ * T_);
    ushort* xb    = (ushort*)ws_end;                           // B*C*T bf16
    ushort* wmat  = xb + (size_t)B_ * C_ * T_;                 // B*T*T bf16
    const size_t needed = (size_t)3 * B_ * T_ * 4
                        + (size_t)B_ * C_ * T_ * 2
                        + (size_t)B_ * T_ * T_ * 2;
    const bool fused = ws_size >= needed;

    norm_kernel<<<dim3(T_ / 256, B_),         256, 0, stream>>>(x, invn);
    xt_kernel  <<<dim3(T_ / 64, C_ / 64, B_), 256, 0, stream>>>(x, invn, xt, fused ? xb : nullptr);

    // segmented: sim half (134 MB) stays L3-resident for its select pass
    for (int seg = 0; seg < 2; ++seg) {
        const int b0 = seg * 8;
        sim_mfma     <<<dim3(2048), 256, 0, stream>>>(xt, sim, b0);
        select_kernel<<<dim3(8 * T_ / 4), 256, 0, stream>>>(sim, cutoff, isv,
                                                            fused ? wmat : nullptr,
                                                            b0 * T_);
    }

    if (fused)
        out_mfma_v2<<<dim3(512),                  256, 0, stream>>>(x, xb, wmat, out0);
    else
        out_mfma   <<<dim3(T_ / 128, C_ / 128, B_), 256, 0, stream>>>(x, sim, cutoff, isv, out0);
}

// Round 11
// 242.629 us; speedup vs baseline: 1.0484x; 1.0484x over previous
//
#include <hip/hip_runtime.h>

#define B_ 16
#define C_ 256
#define T_ 2048
#define K_TOP 256

typedef float  f32x4 __attribute__((ext_vector_type(4)));
typedef short  s16x8 __attribute__((ext_vector_type(8)));

#define GLOAD_LDS16(gsrc, ldst)                                                     \
    __builtin_amdgcn_global_load_lds(                                               \
        (const __attribute__((address_space(1))) void*)(gsrc),                      \
        (__attribute__((address_space(3))) void*)(ldst), 16, 0, 0)

static inline __device__ ushort f2bf(float f) {
    unsigned u = __float_as_uint(f);
    u += 0x7FFF + ((u >> 16) & 1);          // round-to-nearest-even
    return (ushort)(u >> 16);
}

// 16-bit monotone fixed-point key of v (v in [-1.01, 1.03]):
// f = clamp(v+3, [2,4)) has constant exponent -> mantissa bits [22:7] are a
// uniform monotone 16-bit encoding (resolution ~6e-5).
static inline __device__ unsigned key16_of(float v) {
    float f = v + 3.0f;
    f = fminf(fmaxf(f, 2.0f), __uint_as_float(0x407FFFFFu));
    return (__float_as_uint(f) >> 7) & 0xFFFFu;
}

// ---------------------------------------------------------------------------
// K1: inverse column norms  invn[b,t] = 1 / max(||x[b,:,t]||, 1e-12)
// ---------------------------------------------------------------------------
__global__ __launch_bounds__(256) void norm_kernel(const float* __restrict__ x,
                                                   float* __restrict__ invn) {
    const int b = blockIdx.y;
    const int t = blockIdx.x * 256 + threadIdx.x;
    const float* xp = x + (size_t)b * C_ * T_ + t;
    float acc = 0.f;
#pragma unroll 8
    for (int c = 0; c < C_; ++c) {
        float v = xp[(size_t)c * T_];
        acc = fmaf(v, v, acc);
    }
    invn[b * T_ + t] = 1.0f / fmaxf(sqrtf(acc), 1e-12f);
}

// ---------------------------------------------------------------------------
// K1b: xt[b][t][c] = bf16( x[b][c][t] * invn[b][t] )   (transpose + normalize)
//      also xb[b][c][t] = bf16( x[b][c][t] )           (same layout as x)
// ---------------------------------------------------------------------------
__global__ __launch_bounds__(256) void xt_kernel(const float* __restrict__ x,
                                                 const float* __restrict__ invn,
                                                 ushort* __restrict__ xt,
                                                 ushort* __restrict__ xb) {
    const int b  = blockIdx.z;
    const int c0 = blockIdx.y * 64;
    const int t0 = blockIdx.x * 64;
    const float* Xb = x + (size_t)b * C_ * T_;
    ushort* Ob = xt + (size_t)b * T_ * C_;
    __shared__ float tile[64][65];
    const int tid = threadIdx.x;

#pragma unroll
    for (int it = 0; it < 4; ++it) {
        int ch = tid + it * 256;
        int r  = ch >> 4;
        int c4 = (ch & 15) << 2;
        float4 v = *(const float4*)(Xb + (size_t)(c0 + r) * T_ + t0 + c4);
        tile[r][c4 + 0] = v.x;
        tile[r][c4 + 1] = v.y;
        tile[r][c4 + 2] = v.z;
        tile[r][c4 + 3] = v.w;
        if (xb) {
            ushort4 w;
            w.x = f2bf(v.x); w.y = f2bf(v.y); w.z = f2bf(v.z); w.w = f2bf(v.w);
            *(ushort4*)(xb + (size_t)b * C_ * T_ + (size_t)(c0 + r) * T_ + t0 + c4) = w;
        }
    }
    __syncthreads();
#pragma unroll
    for (int it = 0; it < 4; ++it) {
        int ch = tid + it * 256;
        int r2  = ch >> 4;
        int cc4 = (ch & 15) << 2;
        float sc = invn[b * T_ + t0 + r2];
        ushort4 w;
        w.x = f2bf(tile[cc4 + 0][r2] * sc);
        w.y = f2bf(tile[cc4 + 1][r2] * sc);
        w.z = f2bf(tile[cc4 + 2][r2] * sc);
        w.w = f2bf(tile[cc4 + 3][r2] * sc);
        *(ushort4*)(Ob + (size_t)(t0 + r2) * C_ + c0 + cc4) = w;
    }
}

// ---------------------------------------------------------------------------
// K2: sim[b,t,s] = sum_c xt[t][c]*xt[s][c]   (bf16 MFMA, 128x128 tile)
// 1-D grid + XCD-chunked swizzle (R7-proven).
// ---------------------------------------------------------------------------
__global__ __launch_bounds__(256) void sim_mfma(const ushort* __restrict__ xt,
                                                float* __restrict__ sim) {
    const int bid  = blockIdx.x;
    const int bid2 = (bid & 7) * (4096 >> 3) + (bid >> 3);
    const int b    = bid2 >> 8;
    const int rem  = bid2 & 255;
    const int t0   = (rem >> 4) * 128;
    const int s0   = (rem & 15) * 128;
    const ushort* Xb = xt + (size_t)b * T_ * C_;

    __shared__ ushort Al[128 * 64];
    __shared__ ushort Bl[128 * 64];

    const int tid  = threadIdx.x;
    const int lane = tid & 63;
    const int wv   = tid >> 6;
    const int wr   = (wv >> 1) * 64;
    const int wc   = (wv & 1) * 64;
    const int lr   = lane & 15;
    const int lg   = lane >> 4;

    f32x4 acc[4][4] = {};

    for (int k0 = 0; k0 < C_; k0 += 64) {
        __syncthreads();
#pragma unroll
        for (int it = 0; it < 4; ++it) {
            int idx = it * 256 + tid;
            int r   = idx >> 3;
            int c8  = (idx & 7) << 3;
            GLOAD_LDS16(Xb + (size_t)(t0 + r) * C_ + k0 + c8, &Al[idx * 8]);
            GLOAD_LDS16(Xb + (size_t)(s0 + r) * C_ + k0 + c8, &Bl[idx * 8]);
        }
        __syncthreads();
#pragma unroll
        for (int kk = 0; kk < 2; ++kk) {
            s16x8 af[4], bf[4];
#pragma unroll
            for (int i = 0; i < 4; ++i)
                af[i] = *(const s16x8*)&Al[(wr + i * 16 + lr) * 64 + kk * 32 + lg * 8];
#pragma unroll
            for (int j = 0; j < 4; ++j)
                bf[j] = *(const s16x8*)&Bl[(wc + j * 16 + lr) * 64 + kk * 32 + lg * 8];
#pragma unroll
            for (int i = 0; i < 4; ++i)
#pragma unroll
                for (int j = 0; j < 4; ++j)
                    acc[i][j] = __builtin_amdgcn_mfma_f32_16x16x32_bf16(af[i], bf[j], acc[i][j], 0, 0, 0);
        }
    }

    float* Sb = sim + (size_t)b * T_ * T_;
#pragma unroll
    for (int i = 0; i < 4; ++i)
#pragma unroll
        for (int j = 0; j < 4; ++j)
#pragma unroll
            for (int reg = 0; reg < 4; ++reg) {
                int t = t0 + wr + i * 16 + lg * 4 + reg;
                int s = s0 + wc + j * 16 + lr;
                Sb[(size_t)t * T_ + s] = acc[i][j][reg];
            }
}

// ---------------------------------------------------------------------------
// K3 v3: per-row exact-within-6e-5 k-th largest via 2-round radix on 16-bit
// fixed-point keys (uniform bins -> low atomic contention). Wave-per-row.
// Writes bf16 weight row w[t,s]; cutoff = min kept value (exact membership
// equivalence for the fallback path).
// ---------------------------------------------------------------------------
__global__ __launch_bounds__(256) void select_kernel(const float* __restrict__ sim,
                                                     float* __restrict__ cutoff,
                                                     float* __restrict__ isum,
                                                     ushort* __restrict__ wmat) {
    __shared__ int h_all[4][1024];   // per-wave: 256 bins x 4 interleaved copies
    __shared__ int m_all[4][256];    // per-wave: merged bins
    const int tid  = threadIdx.x;
    const int wv   = tid >> 6;
    const int lane = tid & 63;
    int* h = h_all[wv];
    int* m = m_all[wv];
    const int row = blockIdx.x * 4 + wv;
    const float* srow = sim + (size_t)row * T_;

    // load 2048 values (coalesced) + 16-bit keys
    float    vals[32];
    unsigned k16[32];
#pragma unroll
    for (int j = 0; j < 8; ++j) {
        float4 v = ((const float4*)srow)[j * 64 + lane];
        vals[4 * j + 0] = v.x; vals[4 * j + 1] = v.y;
        vals[4 * j + 2] = v.z; vals[4 * j + 3] = v.w;
    }
#pragma unroll
    for (int j = 0; j < 32; ++j) k16[j] = key16_of(vals[j]);

    unsigned prefixB = 0;
    int kk = K_TOP;

#pragma unroll
    for (int round = 0; round < 2; ++round) {
        int4 z = {0, 0, 0, 0};
#pragma unroll
        for (int i = 0; i < 4; ++i) *(int4*)&h[i * 256 + (lane << 2)] = z;
        __builtin_amdgcn_wave_barrier();
        const int copy = lane & 3;
#pragma unroll
        for (int j = 0; j < 32; ++j) {
            unsigned ky = k16[j];
            bool active = (round == 0) || ((ky >> 8) == prefixB);
            int bin = (round == 0) ? (int)(ky >> 8) : (int)(ky & 255u);
            if (active) atomicAdd(&h[(bin << 2) | copy], 1);
        }
        __builtin_amdgcn_wave_barrier();
#pragma unroll
        for (int i = 0; i < 4; ++i) {
            int4 hv = *(const int4*)&h[(i * 64 + lane) << 2];
            m[i * 64 + lane] = hv.x + hv.y + hv.z + hv.w;
        }
        __builtin_amdgcn_wave_barrier();
        int4 mv = *(const int4*)&m[lane << 2];
        int cnt = mv.x + mv.y + mv.z + mv.w;
        int sc = __shfl(cnt, 63 - lane);         // reverse
#pragma unroll
        for (int off = 1; off < 64; off <<= 1) {
            int t = __shfl_up(sc, off);
            if (lane >= off) sc += t;
        }
        int S = __shfl(sc, 63 - lane);           // count with bin >= 4l
        int Sex = S - cnt;
        bool crossing = (S >= kk) && (Sex < kk);
        int sel = 0, kk2 = 0;
        if (crossing) {
            int rem = kk - Sex;
            int a3 = mv.w;
            int a2 = a3 + mv.z;
            int a1 = a2 + mv.y;
            if (rem <= a3)      { sel = 4 * lane + 3; kk2 = rem; }
            else if (rem <= a2) { sel = 4 * lane + 2; kk2 = rem - a3; }
            else if (rem <= a1) { sel = 4 * lane + 1; kk2 = rem - a2; }
            else                { sel = 4 * lane + 0; kk2 = rem - a1; }
        }
        unsigned long long bal = __ballot(crossing);
        int src = (int)(__ffsll((long long)bal) - 1);
        sel = __shfl(sel, src);
        kk2 = __shfl(kk2, src);
        prefixB = (round == 0) ? (unsigned)sel : ((prefixB << 8) | (unsigned)sel);
        kk = kk2;
    }
    const unsigned K16 = prefixB;

    // sum + min of kept values
    float s = 0.f, mn = 3.402823e38f;
#pragma unroll
    for (int j = 0; j < 32; ++j) {
        if (k16[j] >= K16) { s += vals[j]; mn = fminf(mn, vals[j]); }
    }
#pragma unroll
    for (int off = 32; off > 0; off >>= 1) {
        s  += __shfl_down(s, off);
        mn  = fminf(mn, __shfl_down(mn, off));
    }
    float tot = __shfl(s, 0);
    float cut = __shfl(mn, 0);
    if (tot == 0.f) tot = 1.f;
    const float iv = 1.0f / tot;
    if (lane == 0) {
        cutoff[row] = cut;
        isum[row]   = iv;
    }
    if (wmat) {
        ushort* wrow = wmat + (size_t)row * T_;
#pragma unroll
        for (int j = 0; j < 8; ++j) {
            ushort4 wq;
            wq.x = (k16[4*j+0] >= K16) ? f2bf(vals[4*j+0] * iv) : (ushort)0;
            wq.y = (k16[4*j+1] >= K16) ? f2bf(vals[4*j+1] * iv) : (ushort)0;
            wq.z = (k16[4*j+2] >= K16) ? f2bf(vals[4*j+2] * iv) : (ushort)0;
            wq.w = (k16[4*j+3] >= K16) ? f2bf(vals[4*j+3] * iv) : (ushort)0;
            *(ushort4*)(wrow + 4 * (j * 64 + lane)) = wq;
        }
    }
}

// ---------------------------------------------------------------------------
// K4 v2: out0[b,c,t] = x[b,c,t] + sum_s w[t,s]*xb[c,s]   (pure bf16 GEMM)
// 1-D grid + XCD-chunked swizzle (R7-proven).
// ---------------------------------------------------------------------------
__global__ __launch_bounds__(256) void out_mfma_v2(const float* __restrict__ x,
                                                   const ushort* __restrict__ xb,
                                                   const ushort* __restrict__ wmat,
                                                   float* __restrict__ out0) {
    const int bid  = blockIdx.x;
    const int bid2 = (bid & 7) * (512 >> 3) + (bid >> 3);
    const int b    = bid2 >> 5;
    const int rem  = bid2 & 31;
    const int t0   = (rem >> 1) * 128;
    const int c0   = (rem & 1) * 128;
    const float*  Xb = x    + (size_t)b * C_ * T_;
    const ushort* Ab = xb   + (size_t)b * C_ * T_;
    const ushort* Wb = wmat + (size_t)b * T_ * T_;

    __shared__ ushort Al[128 * 64];
    __shared__ ushort Bl[128 * 64];

    const int tid  = threadIdx.x;
    const int lane = tid & 63;
    const int wv   = tid >> 6;
    const int wr   = (wv >> 1) * 64;
    const int wc   = (wv & 1) * 64;
    const int lr   = lane & 15;
    const int lg   = lane >> 4;

    f32x4 acc[4][4] = {};

    for (int k0 = 0; k0 < T_; k0 += 64) {
        __syncthreads();
#pragma unroll
        for (int it = 0; it < 4; ++it) {
            int idx = it * 256 + tid;
            int r   = idx >> 3;
            int c8  = (idx & 7) << 3;
            GLOAD_LDS16(Ab + (size_t)(c0 + r) * T_ + k0 + c8, &Al[idx * 8]);
            GLOAD_LDS16(Wb + (size_t)(t0 + r) * T_ + k0 + c8, &Bl[idx * 8]);
        }
        __syncthreads();
#pragma unroll
        for (int kk = 0; kk < 2; ++kk) {
            s16x8 af[4], bf[4];
#pragma unroll
            for (int i = 0; i < 4; ++i)
                af[i] = *(const s16x8*)&Al[(wr + i * 16 + lr) * 64 + kk * 32 + lg * 8];
#pragma unroll
            for (int j = 0; j < 4; ++j)
                bf[j] = *(const s16x8*)&Bl[(wc + j * 16 + lr) * 64 + kk * 32 + lg * 8];
#pragma unroll
            for (int i = 0; i < 4; ++i)
#pragma unroll
                for (int j = 0; j < 4; ++j)
                    acc[i][j] = __builtin_amdgcn_mfma_f32_16x16x32_bf16(af[i], bf[j], acc[i][j], 0, 0, 0);
        }
    }

#pragma unroll
    for (int i = 0; i < 4; ++i)
#pragma unroll
        for (int j = 0; j < 4; ++j)
#pragma unroll
            for (int reg = 0; reg < 4; ++reg) {
                int c = c0 + wr + i * 16 + lg * 4 + reg;
                int t = t0 + wc + j * 16 + lr;
                out0[((size_t)(b * C_ + c)) * T_ + t] = acc[i][j][reg] + Xb[(size_t)c * T_ + t];
            }
}

// ---------------------------------------------------------------------------
// K4 fallback (R3 version): f32 sim staging with threshold+convert
// ---------------------------------------------------------------------------
__global__ __launch_bounds__(256) void out_mfma(const float* __restrict__ x,
                                                const float* __restrict__ sim,
                                                const float* __restrict__ cutoff,
                                                const float* __restrict__ isum,
                                                float* __restrict__ out0) {
    const int b  = blockIdx.z;
    const int c0 = blockIdx.y * 128;
    const int t0 = blockIdx.x * 128;
    const float* Xb = x   + (size_t)b * C_ * T_;
    const float* Sb = sim + (size_t)b * T_ * T_;

    __shared__ ushort Al[128 * 72];
    __shared__ ushort Bl[128 * 72];
    __shared__ float cut_l[128];
    __shared__ float isv_l[128];

    const int tid  = threadIdx.x;
    const int lane = tid & 63;
    const int wv   = tid >> 6;
    const int wr   = (wv >> 1) * 64;
    const int wc   = (wv & 1) * 64;
    const int lr   = lane & 15;
    const int lg   = lane >> 4;

    if (tid < 128) {
        cut_l[tid] = cutoff[b * T_ + t0 + tid];
        isv_l[tid] = isum  [b * T_ + t0 + tid];
    }

    f32x4 acc[4][4] = {};

    for (int k0 = 0; k0 < T_; k0 += 64) {
        __syncthreads();
#pragma unroll
        for (int it = 0; it < 4; ++it) {
            int ch = tid + it * 256;
            int r  = ch >> 3;
            int c8 = (ch & 7) << 3;
            const float4* pa = (const float4*)(Xb + (size_t)(c0 + r) * T_ + k0 + c8);
            float4 a0 = pa[0], a1 = pa[1];
            ushort aw[8];
            aw[0]=f2bf(a0.x); aw[1]=f2bf(a0.y); aw[2]=f2bf(a0.z); aw[3]=f2bf(a0.w);
            aw[4]=f2bf(a1.x); aw[5]=f2bf(a1.y); aw[6]=f2bf(a1.z); aw[7]=f2bf(a1.w);
            *(s16x8*)&Al[r * 72 + c8] = *(const s16x8*)aw;
            const float4* pb = (const float4*)(Sb + (size_t)(t0 + r) * T_ + k0 + c8);
            float4 b0 = pb[0], b1 = pb[1];
            float cut = cut_l[r], sc = isv_l[r];
            ushort bw[8];
            bw[0]=f2bf(b0.x >= cut ? b0.x * sc : 0.f);
            bw[1]=f2bf(b0.y >= cut ? b0.y * sc : 0.f);
            bw[2]=f2bf(b0.z >= cut ? b0.z * sc : 0.f);
            bw[3]=f2bf(b0.w >= cut ? b0.w * sc : 0.f);
            bw[4]=f2bf(b1.x >= cut ? b1.x * sc : 0.f);
            bw[5]=f2bf(b1.y >= cut ? b1.y * sc : 0.f);
            bw[6]=f2bf(b1.z >= cut ? b1.z * sc : 0.f);
            bw[7]=f2bf(b1.w >= cut ? b1.w * sc : 0.f);
            *(s16x8*)&Bl[r * 72 + c8] = *(const s16x8*)bw;
        }
        __syncthreads();
#pragma unroll
        for (int kk = 0; kk < 2; ++kk) {
            s16x8 af[4], bf[4];
#pragma unroll
            for (int i = 0; i < 4; ++i)
                af[i] = *(const s16x8*)&Al[(wr + i * 16 + lr) * 72 + kk * 32 + lg * 8];
#pragma unroll
            for (int j = 0; j < 4; ++j)
                bf[j] = *(const s16x8*)&Bl[(wc + j * 16 + lr) * 72 + kk * 32 + lg * 8];
#pragma unroll
            for (int i = 0; i < 4; ++i)
#pragma unroll
                for (int j = 0; j < 4; ++j)
                    acc[i][j] = __builtin_amdgcn_mfma_f32_16x16x32_bf16(af[i], bf[j], acc[i][j], 0, 0, 0);
        }
    }

#pragma unroll
    for (int i = 0; i < 4; ++i)
#pragma unroll
        for (int j = 0; j < 4; ++j)
#pragma unroll
            for (int reg = 0; reg < 4; ++reg) {
                int c = c0 + wr + i * 16 + lg * 4 + reg;
                int t = t0 + wc + j * 16 + lr;
                out0[((size_t)(b * C_ + c)) * T_ + t] = acc[i][j][reg] + Xb[(size_t)c * T_ + t];
            }
}

// ---------------------------------------------------------------------------
extern "C" void kernel_launch(void* const* d_in, const int* in_sizes, int n_in,
                              void* d_out, int out_size, void* d_ws, size_t ws_size,
                              hipStream_t stream) {
    const float* x = (const float*)d_in[0];
    float* out0 = (float*)d_out;                              // (B,C,T)
    float* sim  = out0 + (size_t)B_ * C_ * T_;                // (B,T,T)

    ushort* xt = (ushort*)d_out;   // scratch in out0 region until out writes

    // workspace layout
    float* invn   = (float*)d_ws;                             // B*T
    float* cutoff = invn + B_ * T_;                           // B*T
    float* isv    = cutoff + B_ * T_;                          // B*T
    char*  ws_end = (char*)(isv + B_ * T_);
    ushort* xb    = (ushort*)ws_end;                           // B*C*T bf16
    ushort* wmat  = xb + (size_t)B_ * C_ * T_;                 // B*T*T bf16
    const size_t needed = (size_t)3 * B_ * T_ * 4
                        + (size_t)B_ * C_ * T_ * 2
                        + (size_t)B_ * T_ * T_ * 2;
    const bool fused = ws_size >= needed;

    norm_kernel  <<<dim3(T_ / 256, B_),           256, 0, stream>>>(x, invn);
    xt_kernel    <<<dim3(T_ / 64, C_ / 64, B_),   256, 0, stream>>>(x, invn, xt, fused ? xb : nullptr);
    sim_mfma     <<<dim3(4096),                   256, 0, stream>>>(xt, sim);
    select_kernel<<<dim3(B_ * T_ / 4),            256, 0, stream>>>(sim, cutoff, isv, fused ? wmat : nullptr);
    if (fused)
        out_mfma_v2<<<dim3(512),                  256, 0, stream>>>(x, xb, wmat, out0);
    else
        out_mfma   <<<dim3(T_ / 128, C_ / 128, B_), 256, 0, stream>>>(x, sim, cutoff, isv, out0);
}